// Round 8
// baseline (173.648 us; speedup 1.0000x reference)
//
#include <hip/hip_runtime.h>
#include <math.h>

#define NW 917

// Ratio tables: offset, rh, rw, cols(=15-rw)
__constant__ int c_off[13]  = {0,121,241,361,442,522,602,651,696,741,789,837,877};
__constant__ int c_rh[13]   = {4,3,5,6,5,7,8,6,10,7,9,7,10};
__constant__ int c_rw[13]   = {4,5,3,6,7,5,8,10,6,9,7,10,7};
__constant__ int c_cols[13] = {11,10,12,9,8,10,7,5,9,6,8,5,8};

__device__ inline void decode_w(int w, int& r, int& i, int& j){
    int rr = 0;
    #pragma unroll
    for (int k = 1; k < 13; ++k) if (w >= c_off[k]) rr = k;
    int loc = w - c_off[rr];
    int cols = c_cols[rr];
    r = rr; i = loc / cols; j = loc - i * cols;
}

// Monotonic float -> uint; key = (mono << 32) | (0xFFFFFFFF - idx)
__device__ inline unsigned long long nms_key(float v, int w){
    unsigned u = __float_as_uint(v);
    u = (u & 0x80000000u) ? ~u : (u | 0x80000000u);
    return ((unsigned long long)u << 32) | (unsigned)(0xFFFFFFFFu - (unsigned)w);
}

__device__ inline unsigned long long shfl_xor_u64(unsigned long long x, int m){
    unsigned lo = (unsigned)x, hi = (unsigned)(x >> 32);
    lo = __shfl_xor(lo, m);
    hi = __shfl_xor(hi, m);
    return ((unsigned long long)hi << 32) | lo;
}

// K1: block (b,part) sums 128 channels of quarter-plane -> partial[bid][196].
// Flat coalesced: float4 index within quarter = t + 245k (245 = 5*49, so
// each thread keeps a fixed position pos = t%49, channel group cg = t/49).
__global__ __launch_bounds__(256) void chansum_kernel(const float* __restrict__ fm,
                                                      float* __restrict__ partial){
    int t = threadIdx.x;
    int b = blockIdx.x >> 2, part = blockIdx.x & 3;
    __shared__ float4 red[5][49];
    const float4* base = (const float4*)(fm + (size_t)b * 512 * 196) + part * 6272;
    if (t < 245){
        int cg = t / 49;
        float4 a0 = {0.f,0.f,0.f,0.f}, a1 = {0.f,0.f,0.f,0.f};
        #pragma unroll
        for (int k = 0; k < 26; ++k){
            int idx = t + 245 * k;
            if (idx < 6272){
                float4 v = base[idx];
                if (k & 1){ a1.x += v.x; a1.y += v.y; a1.z += v.z; a1.w += v.w; }
                else      { a0.x += v.x; a0.y += v.y; a0.z += v.z; a0.w += v.w; }
            }
        }
        a0.x += a1.x; a0.y += a1.y; a0.z += a1.z; a0.w += a1.w;
        red[cg][t - cg * 49] = a0;
    }
    __syncthreads();
    if (t < 49){
        float4 s = red[0][t];
        #pragma unroll
        for (int k = 1; k < 5; ++k){
            float4 v = red[k][t];
            s.x += v.x; s.y += v.y; s.z += v.z; s.w += v.w;
        }
        ((float4*)partial)[blockIdx.x * 49 + t] = s;
    }
}

// K2: per-b tail: partial sum -> integral -> scores -> {NMS | logits GEMV}
//     -> argmax/mask -> hash GEMV.
__global__ __launch_bounds__(512) void tail_kernel(const float* __restrict__ partial,
                                                   const float* __restrict__ E,
                                                   const float* __restrict__ Wc,
                                                   const float* __restrict__ bc,
                                                   const float* __restrict__ Wh,
                                                   const float* __restrict__ bh,
                                                   float* __restrict__ out_hash,
                                                   float* __restrict__ out_logits,
                                                   float* __restrict__ out_idx,
                                                   float* __restrict__ out_psc,
                                                   float* __restrict__ out_scores){
    int b = blockIdx.x, t = threadIdx.x;
    int lane = t & 63, wv = t >> 6;     // 8 waves

    __shared__ float fmS[196];
    __shared__ float R[14][15];
    __shared__ float I[15][15];
    __shared__ float s[NW];
    __shared__ float emb[512];
    __shared__ float lg[200];
    __shared__ float mk[200];

    // ---- load: partial quarters + embedding ----
    if (t < 196){
        const float* p = partial + (size_t)b * 784 + t;
        fmS[t] = (p[0] + p[196]) + (p[392] + p[588]);
    }
    emb[t] = E[b * 512 + t & 0x7FFFFFFF];  // placeholder avoided below
    __syncthreads();
    __syncthreads();   // (kept structure simple; barriers cheap at 8 waves)

    // NOTE: emb load above is wrong-style; redo cleanly (compiler removes dup).
    emb[t] = E[b * 512 + t];
    __syncthreads();

    // ---- integral image ----
    if (t < 14){
        float run = 0.f;
        R[t][0] = 0.f;
        for (int j = 0; j < 14; ++j){ run += fmS[t * 14 + j]; R[t][j + 1] = run; }
    }
    __syncthreads();
    if (t < 15){
        float run = 0.f;
        I[0][t] = 0.f;
        for (int i = 0; i < 14; ++i){ run += R[i][t]; I[i + 1][t] = run; }
    }
    __syncthreads();

    // ---- 917 window scores ----
    for (int w = t; w < NW; w += 512){
        int r, i, j; decode_w(w, r, i, j);
        int rh = c_rh[r], rw = c_rw[r];
        float sum = I[i + rh][j + rw] - I[i][j + rw] - I[i + rh][j] + I[i][j];
        float sc = sum / (float)(rh * rw);
        s[w] = sc;
        out_scores[(size_t)b * NW + w] = sc;
    }
    __syncthreads();

    // ---- wave 0: register NMS (no barriers) | waves 1-7: logits GEMV ----
    if (wv == 0){
        float sc_[15]; unsigned pk_[15]; int gr_[15];
        #pragma unroll
        for (int m = 0; m < 15; ++m){
            int w = lane + (m << 6);
            bool ok = w < NW;
            int r = 0, i = 0, j = 0;
            if (ok) decode_w(w, r, i, j);
            sc_[m] = ok ? s[w] : 0.f;
            pk_[m] = (unsigned)(i | (j << 4) | (c_rh[r] << 8) | (c_rw[r] << 12));
            gr_[m] = ok ? ((w >= 602) ? 2 : (w >= 361) ? 1 : 0) : 3;
        }
        unsigned vmask = 0x7FFFu;
        int slot = 0;
        #pragma unroll
        for (int g = 0; g < 3; ++g){
            int npick = (g == 0) ? 3 : (g == 1) ? 2 : 1;
            int last  = (g == 0) ? 0 : (g == 1) ? 361 : 602;
            for (int p = 0; p < npick; ++p){
                unsigned long long key = 0ULL;
                #pragma unroll
                for (int m = 0; m < 15; ++m){
                    if (gr_[m] == g && ((vmask >> m) & 1u)){
                        unsigned long long k2 = nms_key(sc_[m], lane + (m << 6));
                        if (k2 > key) key = k2;
                    }
                }
                #pragma unroll
                for (int off = 32; off > 0; off >>= 1){
                    unsigned long long o = shfl_xor_u64(key, off);
                    if (o > key) key = o;
                }
                int pick = (key == 0ULL) ? last
                                         : (int)(0xFFFFFFFFu - (unsigned)(key & 0xFFFFFFFFu));
                last = pick;
                int pr, pi, pj; decode_w(pick, pr, pi, pj);
                float px0 = pi * 32.f, py0 = pj * 32.f;
                float prh = (float)c_rh[pr], prw = (float)c_rw[pr];
                float px1 = px0 + prh * 32.f - 1.f, py1 = py0 + prw * 32.f - 1.f;
                float pa  = prh * prw * 1024.f;
                #pragma unroll
                for (int m = 0; m < 15; ++m){
                    if (gr_[m] == g && ((vmask >> m) & 1u)){
                        unsigned pk = pk_[m];
                        float x0 = (float)(pk & 15u) * 32.f;
                        float y0 = (float)((pk >> 4) & 15u) * 32.f;
                        float rh = (float)((pk >> 8) & 15u);
                        float rw = (float)(pk >> 12);
                        float x1 = x0 + rh * 32.f - 1.f;
                        float y1 = y0 + rw * 32.f - 1.f;
                        float ar = rh * rw * 1024.f;
                        float lx = fminf(x1, px1) - fmaxf(x0, px0) + 1.f;
                        float ly = fminf(y1, py1) - fmaxf(y0, py0) + 1.f;
                        float inter = (lx < 0.f || ly < 0.f) ? 0.f : lx * ly;
                        float iou = inter / (ar + pa - inter);
                        if (iou > 0.25f) vmask &= ~(1u << m);
                    }
                }
                if (lane == 0){
                    out_idx[b * 6 + slot] = (float)pick;
                    out_psc[b * 6 + slot] = s[pick];
                }
                slot++;
            }
        }
    } else {
        // logits GEMV: 16 lanes per row, 4 rows/wave, 7 waves, 8 passes
        int gw  = wv - 1;           // 0..6
        int grp = lane >> 4;        // 0..3
        int s16 = lane & 15;
        const float4* emb4 = (const float4*)emb;
        for (int p = 0; p < 8; ++p){
            int row = p * 28 + gw * 4 + grp;
            if (row < 200){
                const float4* wrow = (const float4*)(Wc + (size_t)row * 512);
                float acc = 0.f;
                #pragma unroll
                for (int k = 0; k < 8; ++k){
                    float4 w = wrow[k * 16 + s16];
                    float4 e = emb4[k * 16 + s16];
                    acc += e.x * w.x + e.y * w.y + e.z * w.z + e.w * w.w;
                }
                acc += __shfl_xor(acc, 1);
                acc += __shfl_xor(acc, 2);
                acc += __shfl_xor(acc, 4);
                acc += __shfl_xor(acc, 8);
                if (s16 == 0){
                    float v = acc + bc[row];
                    lg[row] = v;
                    out_logits[(size_t)b * 200 + row] = v;
                }
            }
        }
    }
    __syncthreads();

    // ---- per-wave redundant argmax over lg[0..199] ----
    {
        unsigned long long key = nms_key(lg[lane], lane);
        unsigned long long k2  = nms_key(lg[lane + 64], lane + 64);
        if (k2 > key) key = k2;
        k2 = nms_key(lg[lane + 128], lane + 128);
        if (k2 > key) key = k2;
        if (lane + 192 < 200){
            k2 = nms_key(lg[lane + 192], lane + 192);
            if (k2 > key) key = k2;
        }
        #pragma unroll
        for (int off = 32; off > 0; off >>= 1){
            unsigned long long o = shfl_xor_u64(key, off);
            if (o > key) key = o;
        }
        int amax = (int)(0xFFFFFFFFu - (unsigned)(key & 0xFFFFFFFFu));
        if (t < 200) mk[t] = lg[t] * (t == amax ? 1.0f : 0.7f);
    }
    __syncthreads();

    // ---- hash GEMV: 8 lanes per row, 48 rows ----
    if (t < 384){
        int row = t >> 3;
        int s8  = t & 7;
        const float4* wrow = (const float4*)(Wh + (size_t)row * 200);
        const float4* mk4  = (const float4*)mk;
        float acc = 0.f;
        #pragma unroll
        for (int m = 0; m < 6; ++m){
            float4 w = wrow[s8 + 8 * m];
            float4 v = mk4[s8 + 8 * m];
            acc += w.x*v.x + w.y*v.y + w.z*v.z + w.w*v.w;
        }
        if (s8 < 2){
            float4 w = wrow[48 + s8];
            float4 v = mk4[48 + s8];
            acc += w.x*v.x + w.y*v.y + w.z*v.z + w.w*v.w;
        }
        acc += __shfl_xor(acc, 1);
        acc += __shfl_xor(acc, 2);
        acc += __shfl_xor(acc, 4);
        if (s8 == 0) out_hash[b * 48 + row] = tanhf(acc + bh[row]);
    }
}

extern "C" void kernel_launch(void* const* d_in, const int* in_sizes, int n_in,
                              void* d_out, int out_size, void* d_ws, size_t ws_size,
                              hipStream_t stream) {
    const float* fm = (const float*)d_in[0];
    const float* E  = (const float*)d_in[1];
    const float* Wc = (const float*)d_in[2];
    const float* bc = (const float*)d_in[3];
    const float* Wh = (const float*)d_in[4];
    const float* bh = (const float*)d_in[5];
    float* out        = (float*)d_out;
    float* out_hash   = out;                 // 256*48   = 12288
    float* out_logits = out + 12288;         // 256*200  = 51200
    float* out_idx    = out + 63488;         // 256*6    = 1536
    float* out_psc    = out + 65024;         // 256*6    = 1536
    float* out_scores = out + 66560;         // 256*917  = 234752
    float* partial    = (float*)d_ws;        // 1024*196 floats = 802816 B

    hipLaunchKernelGGL(chansum_kernel, dim3(1024), dim3(256), 0, stream, fm, partial);
    hipLaunchKernelGGL(tail_kernel,    dim3(256),  dim3(512), 0, stream, partial,
                       E, Wc, bc, Wh, bh,
                       out_hash, out_logits, out_idx, out_psc, out_scores);
}